// Round 16
// baseline (91.042 us; speedup 1.0000x reference)
//
#include <hip/hip_runtime.h>

// B=8, N=256, D=128, 2D=256.
// out = tour [8,256] (arange) ++ improvement_matrix [8,256,256].
//
// R16 = R15 + k_proj GEMM split 256 -> 512 blocks (32x64-output tiles,
// 2 blocks/CU): the 5.5us k_proj (R13 measurement) is serial-chain bound at
// 1 block/CU; halving the tile and doubling residency overlaps the
// Bs-build/As-build/MFMA chains across blocks. k_main = R15 verbatim.
// Budget: fill 41.5 + harness ~24 + k_proj 5.5->~3.7 + k_main ~18.7 = 89.7.

typedef __attribute__((ext_vector_type(8))) short short8;
typedef __attribute__((ext_vector_type(8))) _Float16 half8;
typedef __attribute__((ext_vector_type(2))) _Float16 half2v;
typedef __attribute__((ext_vector_type(2))) short short2v;
typedef __attribute__((ext_vector_type(4))) float floatx4;
typedef __attribute__((ext_vector_type(8))) int intx8;

static __device__ __forceinline__ unsigned short f2bf(float f) {
  unsigned int x = __float_as_uint(f);
  x += 0x7fff + ((x >> 16) & 1);   // RNE fp32 -> bf16
  return (unsigned short)(x >> 16);
}

static __device__ __forceinline__ unsigned short f2h(float f) {
  _Float16 h = (_Float16)f;        // RNE fp32 -> fp16
  return __builtin_bit_cast(unsigned short, h);
}

static __device__ __forceinline__ float fast_tanh(float x) {
  float e = __expf(2.0f * fabsf(x));                       // e^{2|x|}
  float t = 1.0f - 2.0f * __builtin_amdgcn_rcpf(e + 1.0f); // in [0,1)
  return copysignf(t, x);
}

// pack 8 fp16 -> 8 OCP e4m3 bytes.
#if __has_builtin(__builtin_amdgcn_cvt_scalef32_pk_fp8_f16)
// Direct fp16->fp8 (RNE, scale=1.0 identity): 4 ops instead of 12.
static __device__ __forceinline__ long pack_fp8(half8 s) {
  half2v p01 = {s[0], s[1]}, p23 = {s[2], s[3]};
  half2v p45 = {s[4], s[5]}, p67 = {s[6], s[7]};
  short2v lo = __builtin_amdgcn_cvt_scalef32_pk_fp8_f16((short2v)0, p01, 1.0f, false);
  lo = __builtin_amdgcn_cvt_scalef32_pk_fp8_f16(lo, p23, 1.0f, true);
  short2v hi = __builtin_amdgcn_cvt_scalef32_pk_fp8_f16((short2v)0, p45, 1.0f, false);
  hi = __builtin_amdgcn_cvt_scalef32_pk_fp8_f16(hi, p67, 1.0f, true);
  return (long)(unsigned)__builtin_bit_cast(int, lo) |
         ((long)__builtin_bit_cast(int, hi) << 32);
}
#else
// Fallback (R14 path): via f32, v_cvt_pk_fp8_f32.
static __device__ __forceinline__ long pack_fp8(half8 s) {
  int lo = __builtin_amdgcn_cvt_pk_fp8_f32((float)s[0], (float)s[1], 0, false);
  lo = __builtin_amdgcn_cvt_pk_fp8_f32((float)s[2], (float)s[3], lo, true);
  int hi = __builtin_amdgcn_cvt_pk_fp8_f32((float)s[4], (float)s[5], 0, false);
  hi = __builtin_amdgcn_cvt_pk_fp8_f32((float)s[6], (float)s[7], hi, true);
  return (long)(unsigned)lo | ((long)hi << 32);
}
#endif

// async global->LDS DMA, 16B per lane. LDS dest = wave-uniform base + lane*16
// (m104); global src is per-lane. Swizzled layouts are achieved by
// PRE-SWIZZLING the global buffer (m173 pattern), dest stays linear.
static __device__ __forceinline__ void gload_lds16(const void* g, void* l) {
  __builtin_amdgcn_global_load_lds(
      (const __attribute__((address_space(1))) unsigned int*)g,
      (__attribute__((address_space(3))) unsigned int*)l, 16, 0, 0);
}

// ---- k_proj: blocks 0-511 GEMM (32x64 tiles); 512-1025 fill; 1026-1089 W2F8.
// GEMM [2048 rows x 256 K] @ [K x 512 ch] -> PiH | PjH.
//   As (32 rows) built in-block from x; Bs (64 chans) built in-block from W1.
//   2 blocks/CU (48KB LDS) so the build/MFMA chains overlap across blocks.
// PiH LINEAR; PjH chunk-swizzled per row (key row&15): c=chan>>3 ->
//   c'=(c&16)|((c^(row&15))&15), so k_main DMAs the jt tile linearly.
// W2F8 layout (paired for b128 B-frag reads): chan n -> q=n>>5, which=(n>>4)&1,
//   l=n&15; k-chunk c=k>>3, c'=(c&16)|((c^l)&15);
//   byte = q*8192 + l*512 + c'*16 + which*8 + (k&7).
__global__ __launch_bounds__(256) void k_proj(
    const float* __restrict__ x, const float* __restrict__ W1,
    const float* __restrict__ b1, unsigned short* __restrict__ PiH,
    unsigned short* __restrict__ PjH, const float* __restrict__ W2,
    float* __restrict__ out, unsigned char* __restrict__ W2F8) {
  const int tid = threadIdx.x;
  const int bx = blockIdx.x;

  if (bx >= 512) {
    if (bx < 1026) {                       // ---- out-fill, float4 ----
      int t = (bx - 512) * 256 + tid;      // 0..131583
      int e = t * 4;                       // covers 526336 floats exactly
      floatx4 w;
      if (e < 2048) {
        float v = (float)(e & 255);
        w = (floatx4){v, v + 1.f, v + 2.f, v + 3.f};
      } else {
        w = (floatx4)0.f;
      }
      *(floatx4*)(out + e) = w;
    } else {                               // ---- W2 -> fp8(x16) paired ----
      int t = (bx - 1026) * 256 + tid;     // 16384 k-pairs
      int p = t >> 7, n = t & 127;         // p = k/2, n = out channel
      float f0 = W2[(2 * p) * 128 + n] * 16.f;   // x16: e4m3 normal range
      float f1 = W2[(2 * p + 1) * 128 + n] * 16.f;
      int v2 = __builtin_amdgcn_cvt_pk_fp8_f32(f0, f1, 0, false);
      int q = n >> 5, which = (n >> 4) & 1, l = n & 15;
      int c = p >> 2, off = (p & 3) * 2;   // k-chunk = k>>3 = p>>2
      int cs = (c & 16) | ((c ^ l) & 15);
      *(unsigned short*)(W2F8 + q * 8192 + l * 512 + cs * 16 + which * 8 + off) =
          (unsigned short)(v2 & 0xffff);
    }
    return;
  }

  const int mg = bx >> 3;               // 0..63 row-tile (32 rows each)
  const int ng = bx & 7;                // 0..7 channel-tile
  const int wr = tid >> 6, lane = tid & 63, quad = lane >> 4, l15 = lane & 15;

  __shared__ unsigned short As[32 * 256];   // 16KB rows tile (swizzled)
  __shared__ unsigned short Bs[64 * 256];   // 32KB W1-transpose tile (swizzled)

  // ---- Bs: in-block transpose from W1 (R12 path). ----
  {
    const int roff = (ng >= 4) ? 256 : 0;
    const int colbase = (ng & 3) * 64;
    const int rg = tid & 15;
#pragma unroll
    for (int pass = 0; pass < 16; ++pass) {
      const int k = pass * 16 + (tid >> 4);
      const floatx4 f =
          *(const floatx4*)(W1 + (k + roff) * 256 + colbase + rg * 4);
      const int v = k >> 3;
      const int kb = (k & 7) * 2;
#pragma unroll
      for (int j = 0; j < 4; ++j) {
        const int r = rg * 4 + j;
        const int sw = (v & 16) | ((v ^ (r & 15)) & 15);
        *(unsigned short*)((char*)Bs + r * 512 + sw * 16 + kb) = f2bf(f[j]);
      }
    }
  }

  // ---- As: in-block from x (R8 path, 32 rows -> 4 passes) ----
#pragma unroll
  for (int pass = 0; pass < 4; ++pass) {
    const int rr = pass * 8 + (tid >> 5);        // tile row 0..31
    const int grow = mg * 32 + rr;               // global row = b*256+pos
    const int pos = grow & 255, bb = grow >> 8;
    const int v = tid & 31;
    const int pos2 = (v < 16) ? pos : ((pos + 1) & 255);
    const float* src = x + (bb * 256 + pos2) * 128 + (v & 15) * 8;
    const floatx4 f0 = *(const floatx4*)(src);
    const floatx4 f1 = *(const floatx4*)(src + 4);
    union { short8 s; unsigned short u[8]; } o;
    o.u[0] = f2bf(f0[0]); o.u[1] = f2bf(f0[1]);
    o.u[2] = f2bf(f0[2]); o.u[3] = f2bf(f0[3]);
    o.u[4] = f2bf(f1[0]); o.u[5] = f2bf(f1[1]);
    o.u[6] = f2bf(f1[2]); o.u[7] = f2bf(f1[3]);
    const int sw = (v & 16) | ((v ^ (rr & 15)) & 15);
    *(short8*)((char*)As + rr * 512 + sw * 16) = o.s;
  }
  __syncthreads();   // pure LDS-write drain

  floatx4 acc[2];
#pragma unroll
  for (int mt = 0; mt < 2; ++mt) acc[mt] = (floatx4)0.f;

  const char* Ab = (const char*)As;
  const char* Bb = (const char*)Bs + wr * 16 * 512;
  const int base_sw = l15 * 512 + ((quad ^ l15) << 4);

#pragma unroll
  for (int ks = 0; ks < 8; ++ks) {
    const int swz = base_sw ^ (ks << 6);
    short8 bfr = *(const short8*)(Bb + swz);
#pragma unroll
    for (int mt = 0; mt < 2; ++mt) {
      short8 afr = *(const short8*)(Ab + mt * 8192 + swz);
      acc[mt] = __builtin_amdgcn_mfma_f32_16x16x32_bf16(afr, bfr, acc[mt], 0, 0, 0);
    }
  }

  const int ch = ng * 64 + wr * 16 + l15;          // 0..511 (wave-uniform side)
  const float bias = (ch < 256) ? b1[ch] : 0.f;
  const bool isPi = (ch < 256);
  unsigned short* dst = isPi ? PiH : PjH;
  const int chan = ch & 255;
  const int ck = chan >> 3, coff = chan & 7;
#pragma unroll
  for (int mt = 0; mt < 2; ++mt)
#pragma unroll
    for (int r = 0; r < 4; ++r) {
      int row = mg * 32 + mt * 16 + quad * 4 + r;  // global row b*256+pos
      int cpos;
      if (isPi) cpos = chan;
      else {
        int cs = (ck & 16) | ((ck ^ (row & 15)) & 15);
        cpos = cs * 8 + coff;
      }
      dst[row * 256 + cpos] = f2h(acc[mt][r] + bias);
    }
}

// ---- k_main: R15 verbatim (MX-scaled K=128 fp8 MFMA + direct-f16 pack). ----
__global__ __launch_bounds__(256, 3) void k_main(
    const unsigned short* __restrict__ PiH, const unsigned short* __restrict__ PjH,
    const unsigned char* __restrict__ W2F8, const float* __restrict__ b2,
    const float* __restrict__ W3, const float* __restrict__ b3,
    float* __restrict__ outm) {
  const int tid = threadIdx.x;
  const int wr = tid >> 6;              // wave 0..3
  const int lane = tid & 63, quad = lane >> 4, l15 = lane & 15;

  __shared__ unsigned char W2s[32768];  // paired+swizzled fp8
  __shared__ unsigned char PjS[16384];  // 32 rows x 512B, chunk-swizzled
  __shared__ unsigned char PiS[4096];   // 4 waves x 1024B (row duplicated)

  // decode block -> (b, jt, i-base)   [block-uniform except wr]
  const int bid = blockIdx.x;
  const int b = bid / 288;
  const int rem = bid - b * 288;
  int jt = 0, basej = 0;
  if (rem >= 8)   { jt = 1; basej = 8;   }
  if (rem >= 24)  { jt = 2; basej = 24;  }
  if (rem >= 48)  { jt = 3; basej = 48;  }
  if (rem >= 80)  { jt = 4; basej = 80;  }
  if (rem >= 120) { jt = 5; basej = 120; }
  if (rem >= 168) { jt = 6; basej = 168; }
  if (rem >= 224) { jt = 7; basej = 224; }
  const int i = (rem - basej) * 4 + wr;      // 0 .. (jt+1)*32-1 (2 pads/group)

  // stage W2 32KB (2048 chunks) + Pj tile 16KB (1024 chunks) + Pi row/wave
  const unsigned char* pjsrc =
      (const unsigned char*)(PjH + ((b << 8) + jt * 32) * 256);
  const unsigned char* pisrc =
      (const unsigned char*)(PiH + ((b << 8) + i) * 256);
#pragma unroll
  for (int it = 0; it < 8; ++it) {
    const int c = it * 256 + wr * 64 + lane;
    gload_lds16(W2F8 + c * 16, &W2s[(it * 256 + wr * 64) * 16]);
  }
#pragma unroll
  for (int it = 0; it < 4; ++it) {
    const int c = it * 256 + wr * 64 + lane;
    gload_lds16(pjsrc + c * 16, &PjS[(it * 256 + wr * 64) * 16]);
  }
  gload_lds16(pisrc + (lane & 31) * 16, &PiS[wr * 1024]);  // dup in hi 512B
  __syncthreads();

  const char* W2base = (const char*)&W2s[0];
  const char* PjBase = (const char*)&PjS[0];
  const char* PiBase = (const char*)&PiS[0] + wr * 1024 + quad * 16;
  const int sw16 = l15 * 512 + (((quad ^ l15) & 15) << 4);

  floatx4 acc[2][8];
#pragma unroll
  for (int mt = 0; mt < 2; ++mt)
#pragma unroll
    for (int nt = 0; nt < 8; ++nt) acc[mt][nt] = (floatx4)0.f;

  union U4 { uint4 v; half8 h; };
  const int SCL = 0x7f7f7f7f;             // E8M0 = 2^0 = 1.0 in every byte

#pragma unroll
  for (int kh = 0; kh < 2; ++kh) {        // two K=128 halves (ks 0-3 / 4-7)
    // (1) LDS reads: pi/pj for the 4 ks of this half
    U4 piq[4], pj0q[4], pj1q[4];
#pragma unroll
    for (int ks = 0; ks < 4; ++ks) {
      const int ksg = kh * 4 + ks;
      piq[ks].v = *(const uint4*)(PiBase + ksg * 64);
      const char* pj = PjBase + (sw16 ^ (ksg << 6));
      pj0q[ks].v = *(const uint4*)(pj);
      pj1q[ks].v = *(const uint4*)(pj + 8192);
    }
    // (2) build A tuples: pair p of the 8-reg operand = K-block p
    long a0[4], a1[4];
#pragma unroll
    for (int ks = 0; ks < 4; ++ks) {
      const half8 s0 = __builtin_elementwise_max(piq[ks].h + pj0q[ks].h,
                                                 (half8)(_Float16)0);
      const half8 s1 = __builtin_elementwise_max(piq[ks].h + pj1q[ks].h,
                                                 (half8)(_Float16)0);
      a0[ks] = pack_fp8(s0);
      a1[ks] = pack_fp8(s1);
    }
    intx8 A0, A1;
#pragma unroll
    for (int ks = 0; ks < 4; ++ks) {
      A0[2 * ks] = (int)a0[ks];  A0[2 * ks + 1] = (int)(a0[ks] >> 32);
      A1[2 * ks] = (int)a1[ks];  A1[2 * ks + 1] = (int)(a1[ks] >> 32);
    }
    // (3) two nt-halves: read paired B, assemble 8-reg tuples, 16 MFMAs
#pragma unroll
    for (int nh = 0; nh < 2; ++nh) {
#pragma unroll
      for (int q2 = 0; q2 < 2; ++q2) {
        const int q = nh * 2 + q2;         // channel pair (2q, 2q+1)
        uint4 bu[4];
#pragma unroll
        for (int ks = 0; ks < 4; ++ks)
          bu[ks] = *(const uint4*)(W2base + (sw16 ^ ((kh * 4 + ks) << 6)) +
                                   q * 8192);
        intx8 Blo, Bhi;
#pragma unroll
        for (int ks = 0; ks < 4; ++ks) {
          Blo[2 * ks] = (int)bu[ks].x;  Blo[2 * ks + 1] = (int)bu[ks].y;
          Bhi[2 * ks] = (int)bu[ks].z;  Bhi[2 * ks + 1] = (int)bu[ks].w;
        }
        __builtin_amdgcn_s_setprio(1);
        acc[0][2 * q] = __builtin_amdgcn_mfma_scale_f32_16x16x128_f8f6f4(
            A0, Blo, acc[0][2 * q], 0, 0, 0, SCL, 0, SCL);
        acc[1][2 * q] = __builtin_amdgcn_mfma_scale_f32_16x16x128_f8f6f4(
            A1, Blo, acc[1][2 * q], 0, 0, 0, SCL, 0, SCL);
        acc[0][2 * q + 1] = __builtin_amdgcn_mfma_scale_f32_16x16x128_f8f6f4(
            A0, Bhi, acc[0][2 * q + 1], 0, 0, 0, SCL, 0, SCL);
        acc[1][2 * q + 1] = __builtin_amdgcn_mfma_scale_f32_16x16x128_f8f6f4(
            A1, Bhi, acc[1][2 * q + 1], 0, 0, 0, SCL, 0, SCL);
        __builtin_amdgcn_s_setprio(0);
      }
    }
  }

  // epilogue: score[j] = tanh(sum_n W3[n]*relu(C[j,n]/16 + b2[n]) + b3)
  float* orow = outm + ((b << 8) + i) * 256 + jt * 32;
  const float b3v = b3[0];
  const float s16 = 0.0625f;               // undo W2 x16 scale
#pragma unroll
  for (int mt = 0; mt < 2; ++mt) {
    float p0 = 0, p1 = 0, p2 = 0, p3 = 0;
#pragma unroll
    for (int nt = 0; nt < 8; ++nt) {
      float w3v = W3[nt * 16 + l15];
      float b2v = b2[nt * 16 + l15];
      floatx4 a = acc[mt][nt];
      p0 += fmaxf(fmaf(a[0], s16, b2v), 0.f) * w3v;
      p1 += fmaxf(fmaf(a[1], s16, b2v), 0.f) * w3v;
      p2 += fmaxf(fmaf(a[2], s16, b2v), 0.f) * w3v;
      p3 += fmaxf(fmaf(a[3], s16, b2v), 0.f) * w3v;
    }
#pragma unroll
    for (int m = 8; m >= 1; m >>= 1) {   // reduce over the 16 n-cols per quad
      p0 += __shfl_xor(p0, m, 16);
      p1 += __shfl_xor(p1, m, 16);
      p2 += __shfl_xor(p2, m, 16);
      p3 += __shfl_xor(p3, m, 16);
    }
    if (l15 == 0) {
      const int jl = jt * 32 + mt * 16 + quad * 4;   // global j of reg 0
      float ps[4] = {p0, p1, p2, p3};
#pragma unroll
      for (int r = 0; r < 4; ++r) {
        int j = jl + r;
        float sc = fast_tanh(ps[r] + b3v);
        bool valid = (j >= i + 2) && (j - i != 255);
        orow[mt * 16 + quad * 4 + r] = valid ? sc : 0.f;
      }
    }
  }
}

extern "C" void kernel_launch(void* const* d_in, const int* in_sizes, int n_in,
                              void* d_out, int out_size, void* d_ws, size_t ws_size,
                              hipStream_t stream) {
  const float* x  = (const float*)d_in[0];   // [8,256,128]
  const float* W1 = (const float*)d_in[1];   // [512,256]
  const float* b1 = (const float*)d_in[2];   // [256]
  const float* W2 = (const float*)d_in[3];   // [256,128]
  const float* b2 = (const float*)d_in[4];   // [128]
  const float* W3 = (const float*)d_in[5];   // [128]
  const float* b3 = (const float*)d_in[6];   // [1]
  float* out = (float*)d_out;

  // ws (ushort units): PiH 524288 | PjH 524288 | W2F8 32KB
  unsigned short* PiH  = (unsigned short*)d_ws;
  unsigned short* PjH  = PiH + 524288;
  unsigned char*  W2F8 = (unsigned char*)(PjH + 524288);

  k_proj<<<1090, 256, 0, stream>>>(x, W1, b1, PiH, PjH, W2, out, W2F8);
  k_main<<<2304, 256, 0, stream>>>(PiH, PjH, W2F8, b2, W3, b3, out + 2048);
}

// Round 17
// 89.459 us; speedup vs baseline: 1.0177x; 1.0177x over previous
//
#include <hip/hip_runtime.h>

// B=8, N=256, D=128, 2D=256.
// out = tour [8,256] (arange) ++ improvement_matrix [8,256,256].
//
// R17 = R15 verbatim (session best, 89.74us). R16's k_proj 512-block split
// regressed (+1.3us: duplicated Bs-transpose work > chain overlap gained) and
// is reverted. Final budget: fill 41.5 (harness poison) + harness memsets/
// gaps ~24 + k_proj 5.5 + k_main ~18.5. k_main levers exhausted: MX-K=128
// MFMA (R14), direct f16->fp8 pack (R15), LDS-resident inner loop (R5),
// build-ahead pipeline (R7); structural attacks on the remaining stage-drain
// latency failed 6x (R1/R2/R6/R7/R9/R16).

typedef __attribute__((ext_vector_type(8))) short short8;
typedef __attribute__((ext_vector_type(8))) _Float16 half8;
typedef __attribute__((ext_vector_type(2))) _Float16 half2v;
typedef __attribute__((ext_vector_type(2))) short short2v;
typedef __attribute__((ext_vector_type(4))) float floatx4;
typedef __attribute__((ext_vector_type(8))) int intx8;

static __device__ __forceinline__ unsigned short f2bf(float f) {
  unsigned int x = __float_as_uint(f);
  x += 0x7fff + ((x >> 16) & 1);   // RNE fp32 -> bf16
  return (unsigned short)(x >> 16);
}

static __device__ __forceinline__ unsigned short f2h(float f) {
  _Float16 h = (_Float16)f;        // RNE fp32 -> fp16
  return __builtin_bit_cast(unsigned short, h);
}

static __device__ __forceinline__ float fast_tanh(float x) {
  float e = __expf(2.0f * fabsf(x));                       // e^{2|x|}
  float t = 1.0f - 2.0f * __builtin_amdgcn_rcpf(e + 1.0f); // in [0,1)
  return copysignf(t, x);
}

// pack 8 fp16 -> 8 OCP e4m3 bytes.
#if __has_builtin(__builtin_amdgcn_cvt_scalef32_pk_fp8_f16)
// Direct fp16->fp8 (RNE, scale=1.0 identity): 4 ops instead of 12.
static __device__ __forceinline__ long pack_fp8(half8 s) {
  half2v p01 = {s[0], s[1]}, p23 = {s[2], s[3]};
  half2v p45 = {s[4], s[5]}, p67 = {s[6], s[7]};
  short2v lo = __builtin_amdgcn_cvt_scalef32_pk_fp8_f16((short2v)0, p01, 1.0f, false);
  lo = __builtin_amdgcn_cvt_scalef32_pk_fp8_f16(lo, p23, 1.0f, true);
  short2v hi = __builtin_amdgcn_cvt_scalef32_pk_fp8_f16((short2v)0, p45, 1.0f, false);
  hi = __builtin_amdgcn_cvt_scalef32_pk_fp8_f16(hi, p67, 1.0f, true);
  return (long)(unsigned)__builtin_bit_cast(int, lo) |
         ((long)__builtin_bit_cast(int, hi) << 32);
}
#else
// Fallback (R14 path): via f32, v_cvt_pk_fp8_f32.
static __device__ __forceinline__ long pack_fp8(half8 s) {
  int lo = __builtin_amdgcn_cvt_pk_fp8_f32((float)s[0], (float)s[1], 0, false);
  lo = __builtin_amdgcn_cvt_pk_fp8_f32((float)s[2], (float)s[3], lo, true);
  int hi = __builtin_amdgcn_cvt_pk_fp8_f32((float)s[4], (float)s[5], 0, false);
  hi = __builtin_amdgcn_cvt_pk_fp8_f32((float)s[6], (float)s[7], hi, true);
  return (long)(unsigned)lo | ((long)hi << 32);
}
#endif

// async global->LDS DMA, 16B per lane. LDS dest = wave-uniform base + lane*16
// (m104); global src is per-lane. Swizzled layouts are achieved by
// PRE-SWIZZLING the global buffer (m173 pattern), dest stays linear.
static __device__ __forceinline__ void gload_lds16(const void* g, void* l) {
  __builtin_amdgcn_global_load_lds(
      (const __attribute__((address_space(1))) unsigned int*)g,
      (__attribute__((address_space(3))) unsigned int*)l, 16, 0, 0);
}

// ---- k_proj: blocks 0-255 GEMM; 256-769 out-fill; 770-833 W2F8. ------------
// (R12 verbatim — As built in-block from x; Bs built in-block from W1.)
__global__ __launch_bounds__(256) void k_proj(
    const float* __restrict__ x, const float* __restrict__ W1,
    const float* __restrict__ b1, unsigned short* __restrict__ PiH,
    unsigned short* __restrict__ PjH, const float* __restrict__ W2,
    float* __restrict__ out, unsigned char* __restrict__ W2F8) {
  const int tid = threadIdx.x;
  const int bx = blockIdx.x;

  if (bx >= 256) {
    if (bx < 770) {                        // ---- out-fill, float4 ----
      int t = (bx - 256) * 256 + tid;      // 0..131583
      int e = t * 4;                       // covers 526336 floats exactly
      floatx4 w;
      if (e < 2048) {
        float v = (float)(e & 255);
        w = (floatx4){v, v + 1.f, v + 2.f, v + 3.f};
      } else {
        w = (floatx4)0.f;
      }
      *(floatx4*)(out + e) = w;
    } else {                               // ---- W2 -> fp8(x16) paired ----
      int t = (bx - 770) * 256 + tid;      // 16384 k-pairs
      int p = t >> 7, n = t & 127;         // p = k/2, n = out channel
      float f0 = W2[(2 * p) * 128 + n] * 16.f;   // x16: e4m3 normal range
      float f1 = W2[(2 * p + 1) * 128 + n] * 16.f;
      int v2 = __builtin_amdgcn_cvt_pk_fp8_f32(f0, f1, 0, false);
      int q = n >> 5, which = (n >> 4) & 1, l = n & 15;
      int c = p >> 2, off = (p & 3) * 2;   // k-chunk = k>>3 = p>>2
      int cs = (c & 16) | ((c ^ l) & 15);
      *(unsigned short*)(W2F8 + q * 8192 + l * 512 + cs * 16 + which * 8 + off) =
          (unsigned short)(v2 & 0xffff);
    }
    return;
  }

  const int mg = bx >> 3;               // 0..31 row-tile
  const int ng = bx & 7;                // 0..7 channel-tile
  const int wr = tid >> 6, lane = tid & 63, quad = lane >> 4, l15 = lane & 15;

  __shared__ unsigned short As[64 * 256];   // 32KB rows tile (swizzled)
  __shared__ unsigned short Bs[64 * 256];   // 32KB W1-transpose tile (swizzled)

  // ---- Bs: in-block transpose from W1 (R12). ----
  {
    const int roff = (ng >= 4) ? 256 : 0;
    const int colbase = (ng & 3) * 64;
    const int rg = tid & 15;
#pragma unroll
    for (int pass = 0; pass < 16; ++pass) {
      const int k = pass * 16 + (tid >> 4);
      const floatx4 f =
          *(const floatx4*)(W1 + (k + roff) * 256 + colbase + rg * 4);
      const int v = k >> 3;
      const int kb = (k & 7) * 2;
#pragma unroll
      for (int j = 0; j < 4; ++j) {
        const int r = rg * 4 + j;
        const int sw = (v & 16) | ((v ^ (r & 15)) & 15);
        *(unsigned short*)((char*)Bs + r * 512 + sw * 16 + kb) = f2bf(f[j]);
      }
    }
  }

  // ---- As: in-block from x (R8 path, proven) ----
#pragma unroll
  for (int pass = 0; pass < 8; ++pass) {
    const int rr = pass * 8 + (tid >> 5);        // tile row 0..63
    const int grow = mg * 64 + rr;               // global row = b*256+pos
    const int pos = grow & 255, bb = grow >> 8;
    const int v = tid & 31;
    const int pos2 = (v < 16) ? pos : ((pos + 1) & 255);
    const float* src = x + (bb * 256 + pos2) * 128 + (v & 15) * 8;
    const floatx4 f0 = *(const floatx4*)(src);
    const floatx4 f1 = *(const floatx4*)(src + 4);
    union { short8 s; unsigned short u[8]; } o;
    o.u[0] = f2bf(f0[0]); o.u[1] = f2bf(f0[1]);
    o.u[2] = f2bf(f0[2]); o.u[3] = f2bf(f0[3]);
    o.u[4] = f2bf(f1[0]); o.u[5] = f2bf(f1[1]);
    o.u[6] = f2bf(f1[2]); o.u[7] = f2bf(f1[3]);
    const int sw = (v & 16) | ((v ^ (rr & 15)) & 15);
    *(short8*)((char*)As + rr * 512 + sw * 16) = o.s;
  }
  __syncthreads();   // pure LDS-write drain (no DMA in GEMM path now)

  floatx4 acc[4];
#pragma unroll
  for (int mt = 0; mt < 4; ++mt) acc[mt] = (floatx4)0.f;

  const char* Ab = (const char*)As;
  const char* Bb = (const char*)Bs + wr * 16 * 512;
  const int base_sw = l15 * 512 + ((quad ^ l15) << 4);

#pragma unroll
  for (int ks = 0; ks < 8; ++ks) {
    const int swz = base_sw ^ (ks << 6);
    short8 bfr = *(const short8*)(Bb + swz);
#pragma unroll
    for (int mt = 0; mt < 4; ++mt) {
      short8 afr = *(const short8*)(Ab + mt * 8192 + swz);
      acc[mt] = __builtin_amdgcn_mfma_f32_16x16x32_bf16(afr, bfr, acc[mt], 0, 0, 0);
    }
  }

  const int ch = ng * 64 + wr * 16 + l15;          // 0..511 (wave-uniform side)
  const float bias = (ch < 256) ? b1[ch] : 0.f;
  const bool isPi = (ch < 256);
  unsigned short* dst = isPi ? PiH : PjH;
  const int chan = ch & 255;
  const int ck = chan >> 3, coff = chan & 7;
#pragma unroll
  for (int mt = 0; mt < 4; ++mt)
#pragma unroll
    for (int r = 0; r < 4; ++r) {
      int row = mg * 64 + mt * 16 + quad * 4 + r;  // global row b*256+pos
      int cpos;
      if (isPi) cpos = chan;
      else {
        int cs = (ck & 16) | ((ck ^ (row & 15)) & 15);
        cpos = cs * 8 + coff;
      }
      dst[row * 256 + cpos] = f2h(acc[mt][r] + bias);
    }
}

// ---- k_main: MX-scaled K=128 fp8 MFMA (R14) + direct-f16 A-pack (R15). -----
__global__ __launch_bounds__(256, 3) void k_main(
    const unsigned short* __restrict__ PiH, const unsigned short* __restrict__ PjH,
    const unsigned char* __restrict__ W2F8, const float* __restrict__ b2,
    const float* __restrict__ W3, const float* __restrict__ b3,
    float* __restrict__ outm) {
  const int tid = threadIdx.x;
  const int wr = tid >> 6;              // wave 0..3
  const int lane = tid & 63, quad = lane >> 4, l15 = lane & 15;

  __shared__ unsigned char W2s[32768];  // paired+swizzled fp8
  __shared__ unsigned char PjS[16384];  // 32 rows x 512B, chunk-swizzled
  __shared__ unsigned char PiS[4096];   // 4 waves x 1024B (row duplicated)

  // decode block -> (b, jt, i-base)   [block-uniform except wr]
  const int bid = blockIdx.x;
  const int b = bid / 288;
  const int rem = bid - b * 288;
  int jt = 0, basej = 0;
  if (rem >= 8)   { jt = 1; basej = 8;   }
  if (rem >= 24)  { jt = 2; basej = 24;  }
  if (rem >= 48)  { jt = 3; basej = 48;  }
  if (rem >= 80)  { jt = 4; basej = 80;  }
  if (rem >= 120) { jt = 5; basej = 120; }
  if (rem >= 168) { jt = 6; basej = 168; }
  if (rem >= 224) { jt = 7; basej = 224; }
  const int i = (rem - basej) * 4 + wr;      // 0 .. (jt+1)*32-1 (2 pads/group)

  // stage W2 32KB (2048 chunks) + Pj tile 16KB (1024 chunks) + Pi row/wave
  const unsigned char* pjsrc =
      (const unsigned char*)(PjH + ((b << 8) + jt * 32) * 256);
  const unsigned char* pisrc =
      (const unsigned char*)(PiH + ((b << 8) + i) * 256);
#pragma unroll
  for (int it = 0; it < 8; ++it) {
    const int c = it * 256 + wr * 64 + lane;
    gload_lds16(W2F8 + c * 16, &W2s[(it * 256 + wr * 64) * 16]);
  }
#pragma unroll
  for (int it = 0; it < 4; ++it) {
    const int c = it * 256 + wr * 64 + lane;
    gload_lds16(pjsrc + c * 16, &PjS[(it * 256 + wr * 64) * 16]);
  }
  gload_lds16(pisrc + (lane & 31) * 16, &PiS[wr * 1024]);  // dup in hi 512B
  __syncthreads();

  const char* W2base = (const char*)&W2s[0];
  const char* PjBase = (const char*)&PjS[0];
  const char* PiBase = (const char*)&PiS[0] + wr * 1024 + quad * 16;
  const int sw16 = l15 * 512 + (((quad ^ l15) & 15) << 4);

  floatx4 acc[2][8];
#pragma unroll
  for (int mt = 0; mt < 2; ++mt)
#pragma unroll
    for (int nt = 0; nt < 8; ++nt) acc[mt][nt] = (floatx4)0.f;

  union U4 { uint4 v; half8 h; };
  const int SCL = 0x7f7f7f7f;             // E8M0 = 2^0 = 1.0 in every byte

#pragma unroll
  for (int kh = 0; kh < 2; ++kh) {        // two K=128 halves (ks 0-3 / 4-7)
    // (1) LDS reads: pi/pj for the 4 ks of this half
    U4 piq[4], pj0q[4], pj1q[4];
#pragma unroll
    for (int ks = 0; ks < 4; ++ks) {
      const int ksg = kh * 4 + ks;
      piq[ks].v = *(const uint4*)(PiBase + ksg * 64);
      const char* pj = PjBase + (sw16 ^ (ksg << 6));
      pj0q[ks].v = *(const uint4*)(pj);
      pj1q[ks].v = *(const uint4*)(pj + 8192);
    }
    // (2) build A tuples: pair p of the 8-reg operand = K-block p
    long a0[4], a1[4];
#pragma unroll
    for (int ks = 0; ks < 4; ++ks) {
      const half8 s0 = __builtin_elementwise_max(piq[ks].h + pj0q[ks].h,
                                                 (half8)(_Float16)0);
      const half8 s1 = __builtin_elementwise_max(piq[ks].h + pj1q[ks].h,
                                                 (half8)(_Float16)0);
      a0[ks] = pack_fp8(s0);
      a1[ks] = pack_fp8(s1);
    }
    intx8 A0, A1;
#pragma unroll
    for (int ks = 0; ks < 4; ++ks) {
      A0[2 * ks] = (int)a0[ks];  A0[2 * ks + 1] = (int)(a0[ks] >> 32);
      A1[2 * ks] = (int)a1[ks];  A1[2 * ks + 1] = (int)(a1[ks] >> 32);
    }
    // (3) two nt-halves: read paired B, assemble 8-reg tuples, 16 MFMAs
#pragma unroll
    for (int nh = 0; nh < 2; ++nh) {
#pragma unroll
      for (int q2 = 0; q2 < 2; ++q2) {
        const int q = nh * 2 + q2;         // channel pair (2q, 2q+1)
        uint4 bu[4];
#pragma unroll
        for (int ks = 0; ks < 4; ++ks)
          bu[ks] = *(const uint4*)(W2base + (sw16 ^ ((kh * 4 + ks) << 6)) +
                                   q * 8192);
        intx8 Blo, Bhi;
#pragma unroll
        for (int ks = 0; ks < 4; ++ks) {
          Blo[2 * ks] = (int)bu[ks].x;  Blo[2 * ks + 1] = (int)bu[ks].y;
          Bhi[2 * ks] = (int)bu[ks].z;  Bhi[2 * ks + 1] = (int)bu[ks].w;
        }
        __builtin_amdgcn_s_setprio(1);
        acc[0][2 * q] = __builtin_amdgcn_mfma_scale_f32_16x16x128_f8f6f4(
            A0, Blo, acc[0][2 * q], 0, 0, 0, SCL, 0, SCL);
        acc[1][2 * q] = __builtin_amdgcn_mfma_scale_f32_16x16x128_f8f6f4(
            A1, Blo, acc[1][2 * q], 0, 0, 0, SCL, 0, SCL);
        acc[0][2 * q + 1] = __builtin_amdgcn_mfma_scale_f32_16x16x128_f8f6f4(
            A0, Bhi, acc[0][2 * q + 1], 0, 0, 0, SCL, 0, SCL);
        acc[1][2 * q + 1] = __builtin_amdgcn_mfma_scale_f32_16x16x128_f8f6f4(
            A1, Bhi, acc[1][2 * q + 1], 0, 0, 0, SCL, 0, SCL);
        __builtin_amdgcn_s_setprio(0);
      }
    }
  }

  // epilogue: score[j] = tanh(sum_n W3[n]*relu(C[j,n]/16 + b2[n]) + b3)
  float* orow = outm + ((b << 8) + i) * 256 + jt * 32;
  const float b3v = b3[0];
  const float s16 = 0.0625f;               // undo W2 x16 scale
#pragma unroll
  for (int mt = 0; mt < 2; ++mt) {
    float p0 = 0, p1 = 0, p2 = 0, p3 = 0;
#pragma unroll
    for (int nt = 0; nt < 8; ++nt) {
      float w3v = W3[nt * 16 + l15];
      float b2v = b2[nt * 16 + l15];
      floatx4 a = acc[mt][nt];
      p0 += fmaxf(fmaf(a[0], s16, b2v), 0.f) * w3v;
      p1 += fmaxf(fmaf(a[1], s16, b2v), 0.f) * w3v;
      p2 += fmaxf(fmaf(a[2], s16, b2v), 0.f) * w3v;
      p3 += fmaxf(fmaf(a[3], s16, b2v), 0.f) * w3v;
    }
#pragma unroll
    for (int m = 8; m >= 1; m >>= 1) {   // reduce over the 16 n-cols per quad
      p0 += __shfl_xor(p0, m, 16);
      p1 += __shfl_xor(p1, m, 16);
      p2 += __shfl_xor(p2, m, 16);
      p3 += __shfl_xor(p3, m, 16);
    }
    if (l15 == 0) {
      const int jl = jt * 32 + mt * 16 + quad * 4;   // global j of reg 0
      float ps[4] = {p0, p1, p2, p3};
#pragma unroll
      for (int r = 0; r < 4; ++r) {
        int j = jl + r;
        float sc = fast_tanh(ps[r] + b3v);
        bool valid = (j >= i + 2) && (j - i != 255);
        orow[mt * 16 + quad * 4 + r] = valid ? sc : 0.f;
      }
    }
  }
}

extern "C" void kernel_launch(void* const* d_in, const int* in_sizes, int n_in,
                              void* d_out, int out_size, void* d_ws, size_t ws_size,
                              hipStream_t stream) {
  const float* x  = (const float*)d_in[0];   // [8,256,128]
  const float* W1 = (const float*)d_in[1];   // [512,256]
  const float* b1 = (const float*)d_in[2];   // [256]
  const float* W2 = (const float*)d_in[3];   // [256,128]
  const float* b2 = (const float*)d_in[4];   // [128]
  const float* W3 = (const float*)d_in[5];   // [128]
  const float* b3 = (const float*)d_in[6];   // [1]
  float* out = (float*)d_out;

  // ws (ushort units): PiH 524288 | PjH 524288 | W2F8 32KB
  unsigned short* PiH  = (unsigned short*)d_ws;
  unsigned short* PjH  = PiH + 524288;
  unsigned char*  W2F8 = (unsigned char*)(PjH + 524288);

  k_proj<<<834, 256, 0, stream>>>(x, W1, b1, PiH, PjH, W2, out, W2F8);
  k_main<<<2304, 256, 0, stream>>>(PiH, PjH, W2F8, b2, W3, b3, out + 2048);
}